// Round 4
// baseline (1063.836 us; speedup 1.0000x reference)
//
#include <hip/hip_runtime.h>

// HDVLUT: MuLUT-style 2x SR, 3 LUTs (h/d/v) x 8 rotation passes folded into
// one fused pass in the original frame (see R1 header for the derivation).
//
// R1-R3 findings: kernel is NOT latency-bound (MLP 1->8 changed nothing:
// 282 -> 279us). 67M random 16B LUT gathers at 0.39 L1-miss/cyc/CU
// (~2.5cyc/miss) or 12.5 req/cyc/XCD-L2 (78% of 16 channels) is the
// service-rate ceiling. Request count (8/pixel) is algorithmically fixed;
// ideal floor ~218us.
//
// R4: (a) `nt` on LUT gathers — no-allocate/stream in L1, removing L1
// fill+evict work from the miss pipeline (LUT never L1-hits anyway: 3MB vs
// 32KB); (b) 2 pixels per thread with phased vmcnt waits — accumulate pixel
// A under pixel B's gathers, share the stencil, store float4 rows.

typedef float f4 __attribute__((ext_vector_type(4)));

__global__ __launch_bounds__(256, 4) void hdvlut_kernel(
    const int* __restrict__ img,
    const float4* __restrict__ wh,
    const float4* __restrict__ wd,
    const float4* __restrict__ wv,
    float* __restrict__ out)
{
    int idx = blockIdx.x * 256 + threadIdx.x;
    int k = idx & 255;          // x-pair index: pixels (y,2k) and (y,2k+1)
    int y = (idx >> 8) & 511;
    int b = idx >> 17;

    const int* I = img + ((size_t)b << 18);

    int xA = k << 1, xB = xA + 1;
    int c0 = (xA > 0)   ? xA - 1 : 0;
    int c3 = (xB < 511) ? xB + 1 : 511;
    int ym = (y > 0)    ? y - 1 : 0;
    int yp = (y < 511)  ? y + 1 : 511;
    int rM = y << 9, rN = ym << 9, rS = yp << 9;

    // 12-value stencil shared by the pixel pair
    int n0 = I[rN + c0], n1 = I[rN + xA], n2 = I[rN + xB], n3 = I[rN + c3];
    int m0 = I[rM + c0], aA = I[rM + xA], aB = I[rM + xB], m3 = I[rM + c3];
    int s0 = I[rS + c0], s1 = I[rS + xA], s2 = I[rS + xB], s3 = I[rS + c3];

    int aLA = aA << 8, aLB = aB << 8;

    // pixel A partners: E=aB W=m0 S=s1 N=n1 SE=s2 SW=s0 NW=n0 NE=n2
    const float4* pA0 = wh + (aLA + aB);
    const float4* pA1 = wh + (aLA + m0);
    const float4* pA2 = wv + (aLA + s1);
    const float4* pA3 = wv + (aLA + n1);
    const float4* pA4 = wd + (aLA + s2);
    const float4* pA5 = wd + (aLA + s0);
    const float4* pA6 = wd + (aLA + n0);
    const float4* pA7 = wd + (aLA + n2);
    // pixel B partners: E=m3 W=aA S=s2 N=n2 SE=s3 SW=s1 NW=n1 NE=n3
    const float4* pB0 = wh + (aLB + m3);
    const float4* pB1 = wh + (aLB + aA);
    const float4* pB2 = wv + (aLB + s2);
    const float4* pB3 = wv + (aLB + n2);
    const float4* pB4 = wd + (aLB + s3);
    const float4* pB5 = wd + (aLB + s1);
    const float4* pB6 = wd + (aLB + n1);
    const float4* pB7 = wd + (aLB + n3);

    f4 tA0, tA1, tA2, tA3, tA4, tA5, tA6, tA7;
    f4 tB0, tB1, tB2, tB3, tB4, tB5, tB6, tB7;

    // Issue all 16 gathers (nt: no L1 allocation), wait only for the A set.
    asm volatile(
        "global_load_dwordx4 %0, %16, off nt\n\t"
        "global_load_dwordx4 %1, %17, off nt\n\t"
        "global_load_dwordx4 %2, %18, off nt\n\t"
        "global_load_dwordx4 %3, %19, off nt\n\t"
        "global_load_dwordx4 %4, %20, off nt\n\t"
        "global_load_dwordx4 %5, %21, off nt\n\t"
        "global_load_dwordx4 %6, %22, off nt\n\t"
        "global_load_dwordx4 %7, %23, off nt\n\t"
        "global_load_dwordx4 %8, %24, off nt\n\t"
        "global_load_dwordx4 %9, %25, off nt\n\t"
        "global_load_dwordx4 %10, %26, off nt\n\t"
        "global_load_dwordx4 %11, %27, off nt\n\t"
        "global_load_dwordx4 %12, %28, off nt\n\t"
        "global_load_dwordx4 %13, %29, off nt\n\t"
        "global_load_dwordx4 %14, %30, off nt\n\t"
        "global_load_dwordx4 %15, %31, off nt\n\t"
        "s_waitcnt vmcnt(8)"
        : "=&v"(tA0), "=&v"(tA1), "=&v"(tA2), "=&v"(tA3),
          "=&v"(tA4), "=&v"(tA5), "=&v"(tA6), "=&v"(tA7),
          "=&v"(tB0), "=&v"(tB1), "=&v"(tB2), "=&v"(tB3),
          "=&v"(tB4), "=&v"(tB5), "=&v"(tB6), "=&v"(tB7)
        : "v"(pA0), "v"(pA1), "v"(pA2), "v"(pA3),
          "v"(pA4), "v"(pA5), "v"(pA6), "v"(pA7),
          "v"(pB0), "v"(pB1), "v"(pB2), "v"(pB3),
          "v"(pB4), "v"(pB5), "v"(pB6), "v"(pB7));

    // Accumulate pixel A while B's gathers are in flight.
    // Perms: t0 id, t1 rev, t2 id, t3 rev, t4 id, t5 {2,0,3,1}, t6 rev, t7 {1,3,0,2}
    float Ax, Ay, Az, Aw;
    Ax  = tA0.x; Ay  = tA0.y; Az  = tA0.z; Aw  = tA0.w;
    Ax += tA1.w; Ay += tA1.z; Az += tA1.y; Aw += tA1.x;
    Ax += tA2.x; Ay += tA2.y; Az += tA2.z; Aw += tA2.w;
    Ax += tA3.w; Ay += tA3.z; Az += tA3.y; Aw += tA3.x;
    Ax += tA4.x; Ay += tA4.y; Az += tA4.z; Aw += tA4.w;
    Ax += tA5.z; Ay += tA5.x; Az += tA5.w; Aw += tA5.y;
    Ax += tA6.w; Ay += tA6.z; Az += tA6.y; Aw += tA6.x;
    Ax += tA7.y; Ay += tA7.w; Az += tA7.x; Aw += tA7.z;

    // Wait for the B set (value-dep via "+v" pins subsequent reads of tB*).
    asm volatile("s_waitcnt vmcnt(0)"
        : "+v"(tB0), "+v"(tB1), "+v"(tB2), "+v"(tB3),
          "+v"(tB4), "+v"(tB5), "+v"(tB6), "+v"(tB7));

    float Bx, By, Bz, Bw;
    Bx  = tB0.x; By  = tB0.y; Bz  = tB0.z; Bw  = tB0.w;
    Bx += tB1.w; By += tB1.z; Bz += tB1.y; Bw += tB1.x;
    Bx += tB2.x; By += tB2.y; Bz += tB2.z; Bw += tB2.w;
    Bx += tB3.w; By += tB3.z; Bz += tB3.y; Bw += tB3.x;
    Bx += tB4.x; By += tB4.y; Bz += tB4.z; Bw += tB4.w;
    Bx += tB5.z; By += tB5.x; Bz += tB5.w; Bw += tB5.y;
    Bx += tB6.w; By += tB6.z; Bz += tB6.y; Bw += tB6.x;
    Bx += tB7.y; By += tB7.w; Bz += tB7.x; Bw += tB7.z;

    // Output rows 2y and 2y+1, cols 4k..4k+3 (A then B), all /2.
    size_t orow = ((((size_t)b << 10) + (y << 1)) << 10) + (k << 2);
    *(float4*)(out + orow)        = make_float4(Ax * 0.5f, Ay * 0.5f, Bx * 0.5f, By * 0.5f);
    *(float4*)(out + orow + 1024) = make_float4(Az * 0.5f, Aw * 0.5f, Bz * 0.5f, Bw * 0.5f);
}

extern "C" void kernel_launch(void* const* d_in, const int* in_sizes, int n_in,
                              void* d_out, int out_size, void* d_ws, size_t ws_size,
                              hipStream_t stream) {
    const int*    img = (const int*)d_in[0];
    const float4* wh  = (const float4*)d_in[1];
    const float4* wd  = (const float4*)d_in[2];
    const float4* wv  = (const float4*)d_in[3];
    float* out = (float*)d_out;

    int total  = in_sizes[0] / 2;      // one thread per pixel pair
    int blocks = total / 256;
    hipLaunchKernelGGL(hdvlut_kernel, dim3(blocks), dim3(256), 0, stream,
                       img, wh, wd, wv, out);
}

// Round 5
// 394.567 us; speedup vs baseline: 2.6962x; 2.6962x over previous
//
#include <hip/hip_runtime.h>

// HDVLUT: MuLUT-style 2x SR, 3 LUTs (h/d/v) x 8 rotation passes folded into
// one fused pass in the original frame (see R1 header for the derivation).
//
// R1-R3: not latency-bound (MLP 1->8: 282->279us). Limiter is a fixed-rate
// service stage ~2.56 cyc per lane-gather per CU.
// R4: `nt` on gathers = non-temporal THROUGH L2 -> LUT uncached anywhere,
// FETCH 70MB->2.28GB, 934us. Never use nt on a hot LUT.
// R5: `sc0` (SE-scope) loads instead: bypass per-CU L1 (no L1 fill/evict
// work for guaranteed-miss random gathers) but still allocate in the 4MiB
// per-XCD L2 that fully holds the 3MB LUTs.

typedef float f4 __attribute__((ext_vector_type(4)));

__global__ __launch_bounds__(256, 4) void hdvlut_kernel(
    const int* __restrict__ img,
    const float4* __restrict__ wh,
    const float4* __restrict__ wd,
    const float4* __restrict__ wv,
    float* __restrict__ out)
{
    int idx = blockIdx.x * 256 + threadIdx.x;
    int k = idx & 255;          // x-pair index: pixels (y,2k) and (y,2k+1)
    int y = (idx >> 8) & 511;
    int b = idx >> 17;

    const int* I = img + ((size_t)b << 18);

    int xA = k << 1, xB = xA + 1;
    int c0 = (xA > 0)   ? xA - 1 : 0;
    int c3 = (xB < 511) ? xB + 1 : 511;
    int ym = (y > 0)    ? y - 1 : 0;
    int yp = (y < 511)  ? y + 1 : 511;
    int rM = y << 9, rN = ym << 9, rS = yp << 9;

    // 12-value stencil shared by the pixel pair
    int n0 = I[rN + c0], n1 = I[rN + xA], n2 = I[rN + xB], n3 = I[rN + c3];
    int m0 = I[rM + c0], aA = I[rM + xA], aB = I[rM + xB], m3 = I[rM + c3];
    int s0 = I[rS + c0], s1 = I[rS + xA], s2 = I[rS + xB], s3 = I[rS + c3];

    int aLA = aA << 8, aLB = aB << 8;

    // pixel A partners: E=aB W=m0 S=s1 N=n1 SE=s2 SW=s0 NW=n0 NE=n2
    const float4* pA0 = wh + (aLA + aB);
    const float4* pA1 = wh + (aLA + m0);
    const float4* pA2 = wv + (aLA + s1);
    const float4* pA3 = wv + (aLA + n1);
    const float4* pA4 = wd + (aLA + s2);
    const float4* pA5 = wd + (aLA + s0);
    const float4* pA6 = wd + (aLA + n0);
    const float4* pA7 = wd + (aLA + n2);
    // pixel B partners: E=m3 W=aA S=s2 N=n2 SE=s3 SW=s1 NW=n1 NE=n3
    const float4* pB0 = wh + (aLB + m3);
    const float4* pB1 = wh + (aLB + aA);
    const float4* pB2 = wv + (aLB + s2);
    const float4* pB3 = wv + (aLB + n2);
    const float4* pB4 = wd + (aLB + s3);
    const float4* pB5 = wd + (aLB + s1);
    const float4* pB6 = wd + (aLB + n1);
    const float4* pB7 = wd + (aLB + n3);

    f4 tA0, tA1, tA2, tA3, tA4, tA5, tA6, tA7;
    f4 tB0, tB1, tB2, tB3, tB4, tB5, tB6, tB7;

    // Issue all 16 gathers (sc0: SE scope, skip L1, allocate in L2),
    // wait only for the A set.
    asm volatile(
        "global_load_dwordx4 %0, %16, off sc0\n\t"
        "global_load_dwordx4 %1, %17, off sc0\n\t"
        "global_load_dwordx4 %2, %18, off sc0\n\t"
        "global_load_dwordx4 %3, %19, off sc0\n\t"
        "global_load_dwordx4 %4, %20, off sc0\n\t"
        "global_load_dwordx4 %5, %21, off sc0\n\t"
        "global_load_dwordx4 %6, %22, off sc0\n\t"
        "global_load_dwordx4 %7, %23, off sc0\n\t"
        "global_load_dwordx4 %8, %24, off sc0\n\t"
        "global_load_dwordx4 %9, %25, off sc0\n\t"
        "global_load_dwordx4 %10, %26, off sc0\n\t"
        "global_load_dwordx4 %11, %27, off sc0\n\t"
        "global_load_dwordx4 %12, %28, off sc0\n\t"
        "global_load_dwordx4 %13, %29, off sc0\n\t"
        "global_load_dwordx4 %14, %30, off sc0\n\t"
        "global_load_dwordx4 %15, %31, off sc0\n\t"
        "s_waitcnt vmcnt(8)"
        : "=&v"(tA0), "=&v"(tA1), "=&v"(tA2), "=&v"(tA3),
          "=&v"(tA4), "=&v"(tA5), "=&v"(tA6), "=&v"(tA7),
          "=&v"(tB0), "=&v"(tB1), "=&v"(tB2), "=&v"(tB3),
          "=&v"(tB4), "=&v"(tB5), "=&v"(tB6), "=&v"(tB7)
        : "v"(pA0), "v"(pA1), "v"(pA2), "v"(pA3),
          "v"(pA4), "v"(pA5), "v"(pA6), "v"(pA7),
          "v"(pB0), "v"(pB1), "v"(pB2), "v"(pB3),
          "v"(pB4), "v"(pB5), "v"(pB6), "v"(pB7));

    // Accumulate pixel A while B's gathers are in flight.
    // Perms: t0 id, t1 rev, t2 id, t3 rev, t4 id, t5 {2,0,3,1}, t6 rev, t7 {1,3,0,2}
    float Ax, Ay, Az, Aw;
    Ax  = tA0.x; Ay  = tA0.y; Az  = tA0.z; Aw  = tA0.w;
    Ax += tA1.w; Ay += tA1.z; Az += tA1.y; Aw += tA1.x;
    Ax += tA2.x; Ay += tA2.y; Az += tA2.z; Aw += tA2.w;
    Ax += tA3.w; Ay += tA3.z; Az += tA3.y; Aw += tA3.x;
    Ax += tA4.x; Ay += tA4.y; Az += tA4.z; Aw += tA4.w;
    Ax += tA5.z; Ay += tA5.x; Az += tA5.w; Aw += tA5.y;
    Ax += tA6.w; Ay += tA6.z; Az += tA6.y; Aw += tA6.x;
    Ax += tA7.y; Ay += tA7.w; Az += tA7.x; Aw += tA7.z;

    // Wait for the B set (value-dep via "+v" pins subsequent reads of tB*).
    asm volatile("s_waitcnt vmcnt(0)"
        : "+v"(tB0), "+v"(tB1), "+v"(tB2), "+v"(tB3),
          "+v"(tB4), "+v"(tB5), "+v"(tB6), "+v"(tB7));

    float Bx, By, Bz, Bw;
    Bx  = tB0.x; By  = tB0.y; Bz  = tB0.z; Bw  = tB0.w;
    Bx += tB1.w; By += tB1.z; Bz += tB1.y; Bw += tB1.x;
    Bx += tB2.x; By += tB2.y; Bz += tB2.z; Bw += tB2.w;
    Bx += tB3.w; By += tB3.z; Bz += tB3.y; Bw += tB3.x;
    Bx += tB4.x; By += tB4.y; Bz += tB4.z; Bw += tB4.w;
    Bx += tB5.z; By += tB5.x; Bz += tB5.w; Bw += tB5.y;
    Bx += tB6.w; By += tB6.z; Bz += tB6.y; Bw += tB6.x;
    Bx += tB7.y; By += tB7.w; Bz += tB7.x; Bw += tB7.z;

    // Output rows 2y and 2y+1, cols 4k..4k+3 (A then B), all /2.
    size_t orow = ((((size_t)b << 10) + (y << 1)) << 10) + (k << 2);
    *(float4*)(out + orow)        = make_float4(Ax * 0.5f, Ay * 0.5f, Bx * 0.5f, By * 0.5f);
    *(float4*)(out + orow + 1024) = make_float4(Az * 0.5f, Aw * 0.5f, Bz * 0.5f, Bw * 0.5f);
}

extern "C" void kernel_launch(void* const* d_in, const int* in_sizes, int n_in,
                              void* d_out, int out_size, void* d_ws, size_t ws_size,
                              hipStream_t stream) {
    const int*    img = (const int*)d_in[0];
    const float4* wh  = (const float4*)d_in[1];
    const float4* wd  = (const float4*)d_in[2];
    const float4* wv  = (const float4*)d_in[3];
    float* out = (float*)d_out;

    int total  = in_sizes[0] / 2;      // one thread per pixel pair
    int blocks = total / 256;
    hipLaunchKernelGGL(hdvlut_kernel, dim3(blocks), dim3(256), 0, stream,
                       img, wh, wd, wv, out);
}

// Round 6
// 306.238 us; speedup vs baseline: 3.4739x; 1.2884x over previous
//
#include <hip/hip_runtime.h>

// HDVLUT: MuLUT-style 2x SR, 3 LUTs (h/d/v) x 8 rotation passes folded into
// one fused pass (R1 derivation, ref-verified).
//
// R1-R5 findings: throughput pinned at 279-283us regardless of MLP (1->8),
// L1 policy (sc0), occupancy (87%->39%), or pixels/thread. Limiter = shared
// divergent-gather service rate: 67.1M lane-requests ~= 12.4 req/cyc/XCD.
// `nt` bypasses L2 entirely (R4: FETCH 70MB->2.28GB, 934us) - never on LUTs.
//
// R6: HALVE THE REQUEST COUNT via transpose-merged LUTs.
// Every key (p,q) is consulted twice by adjacent pixels with transposed keys
// (E<->W, S<->N, SE<->NW, SW<->NE). Prep kernel builds fp16 merged LUTs
// X2[p*256+q] = {x(p,q).4, x(q,p).4} (8 x fp16 = 16B = ONE request serving
// TWO lookups). Each thread fetches its 4 forward edges; backward halves are
// exchanged via LDS within a 16x16 tile; tile-border threads direct-fetch
// (+9%). 8 req/px -> 4.37 req/px.

typedef _Float16 h8 __attribute__((ext_vector_type(8)));
typedef _Float16 h4 __attribute__((ext_vector_type(4)));

// ---------------- prep: build merged fp16 LUTs in workspace ----------------
// ws layout (entries of 16B): [H2 | V2 | D2] at 0, 65536, 131072.
__global__ __launch_bounds__(256) void hdvlut_prep(
    const float4* __restrict__ wh,
    const float4* __restrict__ wd,
    const float4* __restrict__ wv,
    h8* __restrict__ ws)
{
    int idx = blockIdx.x * 256 + threadIdx.x;   // 0 .. 3*65536-1
    int lut = idx >> 16;
    int pq  = idx & 65535;
    int p = pq >> 8, q = pq & 255;
    const float4* src = (lut == 0) ? wh : (lut == 1) ? wv : wd;
    float4 f = src[pq];                // (p,q)  coalesced
    float4 g = src[(q << 8) | p];      // (q,p)  strided, L2-resident
    h8 e;
    e[0] = (_Float16)f.x; e[1] = (_Float16)f.y;
    e[2] = (_Float16)f.z; e[3] = (_Float16)f.w;
    e[4] = (_Float16)g.x; e[5] = (_Float16)g.y;
    e[6] = (_Float16)g.z; e[7] = (_Float16)g.w;
    ws[idx] = e;
}

// ---------------- main: 16x16 tile, LDS backward-half exchange -------------
__global__ __launch_bounds__(256) void hdvlut_merged(
    const int* __restrict__ img,
    const h8* __restrict__ W2,
    float* __restrict__ out)
{
    __shared__ h4 bwdE[256], bwdS[256], bwdSE[256], bwdSW[256];

    int t  = threadIdx.x;
    int tx = t & 15, ty = t >> 4;
    int blk   = blockIdx.x;            // b*1024 + tileY*32 + tileX
    int tileX = blk & 31;
    int tileY = (blk >> 5) & 31;
    int b     = blk >> 10;
    int x = (tileX << 4) | tx;
    int y = (tileY << 4) | ty;

    const int* I = img + ((size_t)b << 18);

    int xm = (x > 0)   ? x - 1 : 0;
    int xp = (x < 511) ? x + 1 : 511;
    int ym = (y > 0)   ? y - 1 : 0;
    int yp = (y < 511) ? y + 1 : 511;
    int rM = y << 9, rN = ym << 9, rS = yp << 9;

    int a   = I[rM + x];
    int aE  = I[rM + xp], aW  = I[rM + xm];
    int aS  = I[rS + x ], aN  = I[rN + x ];
    int aSE = I[rS + xp], aSW = I[rS + xm];
    int aNW = I[rN + xm], aNE = I[rN + xp];
    int aL = a << 8;

    const h8* H2 = W2;
    const h8* V2 = W2 + 65536;
    const h8* D2 = W2 + 131072;

    // Forward merged fetches: fwd half = this pixel's lookup,
    // bwd half = the neighbor's mirrored lookup.
    h8 fE  = H2[aL + aE ];
    h8 fS  = V2[aL + aS ];
    h8 fSE = D2[aL + aSE];
    h8 fSW = D2[aL + aSW];

    // Tile-border direct fetches (fwd halves used; image-border clamping is
    // already baked into aW/aN/aNW/aNE; image borders coincide with tile
    // borders so in-tile LDS values are always genuine).
    bool bW  = (tx == 0);
    bool bN  = (ty == 0);
    bool bNW = bN || bW;
    bool bNE = bN || (tx == 15);
    h8 dW = {}, dN = {}, dNW = {}, dNE = {};
    if (bW)  dW  = H2[aL + aW ];
    if (bN)  dN  = V2[aL + aN ];
    if (bNW) dNW = D2[aL + aNW];
    if (bNE) dNE = D2[aL + aNE];

    bwdE [t] = __builtin_shufflevector(fE,  fE,  4, 5, 6, 7);
    bwdS [t] = __builtin_shufflevector(fS,  fS,  4, 5, 6, 7);
    bwdSE[t] = __builtin_shufflevector(fSE, fSE, 4, 5, 6, 7);
    bwdSW[t] = __builtin_shufflevector(fSW, fSW, 4, 5, 6, 7);
    __syncthreads();

    // Neighbor LDS slots (indices clamped; clamped reads are discarded by the
    // border selects below).
    int txm = (tx > 0)  ? tx - 1 : 0;
    int txp = (tx < 15) ? tx + 1 : 15;
    int tym = (ty > 0)  ? ty - 1 : 0;
    h4 lW  = bwdE [(ty  << 4) | txm];
    h4 lN  = bwdS [(tym << 4) | tx ];
    h4 lNW = bwdSE[(tym << 4) | txm];
    h4 lNE = bwdSW[(tym << 4) | txp];

    h4 vW  = bW  ? __builtin_shufflevector(dW,  dW,  0, 1, 2, 3) : lW;
    h4 vN  = bN  ? __builtin_shufflevector(dN,  dN,  0, 1, 2, 3) : lN;
    h4 vNW = bNW ? __builtin_shufflevector(dNW, dNW, 0, 1, 2, 3) : lNW;
    h4 vNE = bNE ? __builtin_shufflevector(dNE, dNE, 0, 1, 2, 3) : lNE;

    // Accumulate (perms ref-verified in R1):
    float ax, ay, az, aw;
    // E: identity
    ax  = (float)fE[0];  ay  = (float)fE[1];  az  = (float)fE[2];  aw  = (float)fE[3];
    // S: identity
    ax += (float)fS[0];  ay += (float)fS[1];  az += (float)fS[2];  aw += (float)fS[3];
    // SE: identity
    ax += (float)fSE[0]; ay += (float)fSE[1]; az += (float)fSE[2]; aw += (float)fSE[3];
    // SW: {2,0,3,1}
    ax += (float)fSW[2]; ay += (float)fSW[0]; az += (float)fSW[3]; aw += (float)fSW[1];
    // W: reversed
    ax += (float)vW[3];  ay += (float)vW[2];  az += (float)vW[1];  aw += (float)vW[0];
    // N: reversed
    ax += (float)vN[3];  ay += (float)vN[2];  az += (float)vN[1];  aw += (float)vN[0];
    // NW: reversed
    ax += (float)vNW[3]; ay += (float)vNW[2]; az += (float)vNW[1]; aw += (float)vNW[0];
    // NE: {1,3,0,2}
    ax += (float)vNE[1]; ay += (float)vNE[3]; az += (float)vNE[0]; aw += (float)vNE[2];

    size_t obase = ((((size_t)b << 10) + (y << 1)) << 10) + (x << 1);
    *(float2*)(out + obase)        = make_float2(ax * 0.5f, ay * 0.5f);
    *(float2*)(out + obase + 1024) = make_float2(az * 0.5f, aw * 0.5f);
}

// ---------------- fallback (R1 kernel) if workspace is too small -----------
__global__ __launch_bounds__(256) void hdvlut_plain(
    const int* __restrict__ img,
    const float4* __restrict__ wh,
    const float4* __restrict__ wd,
    const float4* __restrict__ wv,
    float* __restrict__ out)
{
    int idx = blockIdx.x * 256 + threadIdx.x;
    int x = idx & 511, y = (idx >> 9) & 511, b = idx >> 18;
    const int* I = img + ((size_t)b << 18);
    int row = y << 9;
    int xm = (x > 0) ? x - 1 : 0, xp = (x < 511) ? x + 1 : 511;
    int ym = (y > 0) ? y - 1 : 0, yp = (y < 511) ? y + 1 : 511;
    int rN = ym << 9, rS = yp << 9;
    int a = I[row|x], E = I[row|xp], W_ = I[row|xm], S = I[rS|x], N_ = I[rN|x];
    int SE = I[rS|xp], SW = I[rS|xm], NW = I[rN|xm], NE = I[rN|xp];
    int aL = a << 8;
    float4 t; float ax, ay, az, aw;
    t = wh[aL+E ]; ax  = t.x; ay  = t.y; az  = t.z; aw  = t.w;
    t = wh[aL+W_]; ax += t.w; ay += t.z; az += t.y; aw += t.x;
    t = wv[aL+S ]; ax += t.x; ay += t.y; az += t.z; aw += t.w;
    t = wv[aL+N_]; ax += t.w; ay += t.z; az += t.y; aw += t.x;
    t = wd[aL+SE]; ax += t.x; ay += t.y; az += t.z; aw += t.w;
    t = wd[aL+SW]; ax += t.z; ay += t.x; az += t.w; aw += t.y;
    t = wd[aL+NW]; ax += t.w; ay += t.z; az += t.y; aw += t.x;
    t = wd[aL+NE]; ax += t.y; ay += t.w; az += t.x; aw += t.z;
    size_t obase = ((((size_t)b << 10) + (y << 1)) << 10) + (x << 1);
    *(float2*)(out + obase)        = make_float2(ax*0.5f, ay*0.5f);
    *(float2*)(out + obase + 1024) = make_float2(az*0.5f, aw*0.5f);
}

extern "C" void kernel_launch(void* const* d_in, const int* in_sizes, int n_in,
                              void* d_out, int out_size, void* d_ws, size_t ws_size,
                              hipStream_t stream) {
    const int*    img = (const int*)d_in[0];
    const float4* wh  = (const float4*)d_in[1];
    const float4* wd  = (const float4*)d_in[2];
    const float4* wv  = (const float4*)d_in[3];
    float* out = (float*)d_out;

    int total = in_sizes[0];                   // B * 512 * 512
    size_t need = (size_t)3 * 65536 * 16;      // 3 MB merged LUTs
    if (ws_size >= need) {
        h8* W2 = (h8*)d_ws;
        hipLaunchKernelGGL(hdvlut_prep, dim3(768), dim3(256), 0, stream,
                           wh, wd, wv, W2);
        hipLaunchKernelGGL(hdvlut_merged, dim3(total / 256), dim3(256), 0, stream,
                           img, W2, out);
    } else {
        hipLaunchKernelGGL(hdvlut_plain, dim3(total / 256), dim3(256), 0, stream,
                           img, wh, wd, wv, out);
    }
}